// Round 1
// baseline (2619.435 us; speedup 1.0000x reference)
//
#include <hip/hip_runtime.h>
#include <hip/hip_bf16.h>
#include <math.h>

#define NNODES 100000
#define NEDGES 500000
#define DIN 776
#define DH 128
#define NHEAD 4
#define CH 32
#define NEG_SLOPE 0.2f
#define LN_EPS 1e-5f

// ---------------- GEMM: C[n,128] = A[n,K] * B[K,128] (+ bias) ----------------
// 16 rows per block, 128 threads (one col each), each thread computes 16 outputs.
template<int K, bool BIAS>
__global__ __launch_bounds__(128) void gemm128(const float* __restrict__ A,
                                               const float* __restrict__ B,
                                               const float* __restrict__ bias,
                                               float* __restrict__ C) {
    __shared__ float As[16 * K];
    const int row0 = blockIdx.x * 16;
    const int tid = threadIdx.x;

    // cooperative load of 16 rows of A into LDS (rows are contiguous)
    const float4* A4 = reinterpret_cast<const float4*>(A + (size_t)row0 * K);
    float4* As4 = reinterpret_cast<float4*>(As);
    const int n4 = 16 * K / 4;
    for (int i = tid; i < n4; i += 128) As4[i] = A4[i];
    __syncthreads();

    float acc[16];
#pragma unroll
    for (int r = 0; r < 16; ++r) acc[r] = 0.f;

    const int col = tid;
    for (int k = 0; k < K; k += 4) {
        const float b0 = B[(k + 0) * 128 + col];
        const float b1 = B[(k + 1) * 128 + col];
        const float b2 = B[(k + 2) * 128 + col];
        const float b3 = B[(k + 3) * 128 + col];
#pragma unroll
        for (int r = 0; r < 16; ++r) {
            const float4 a = *reinterpret_cast<const float4*>(&As[r * K + k]);
            acc[r] += a.x * b0;
            acc[r] += a.y * b1;
            acc[r] += a.z * b2;
            acc[r] += a.w * b3;
        }
    }
    const float bv = BIAS ? bias[col] : 0.f;
#pragma unroll
    for (int r = 0; r < 16; ++r) C[(size_t)(row0 + r) * 128 + col] = acc[r] + bv;
}

// ---------------- LayerNorm (wave per row, optionally in-place) ----------------
__global__ __launch_bounds__(256) void ln_kernel(const float* __restrict__ in,
                                                 const float* __restrict__ g,
                                                 const float* __restrict__ b,
                                                 float* __restrict__ out, int n) {
    const int wave = (blockIdx.x * blockDim.x + threadIdx.x) >> 6;
    const int lane = threadIdx.x & 63;
    if (wave >= n) return;
    const float2 v = reinterpret_cast<const float2*>(in + (size_t)wave * 128)[lane];
    float s = v.x + v.y;
    float sq = v.x * v.x + v.y * v.y;
#pragma unroll
    for (int o = 32; o; o >>= 1) { s += __shfl_xor(s, o); sq += __shfl_xor(sq, o); }
    const float mu = s * (1.f / 128.f);
    const float var = sq * (1.f / 128.f) - mu * mu;
    const float rinv = rsqrtf(var + LN_EPS);
    const float2 gg = reinterpret_cast<const float2*>(g)[lane];
    const float2 bb = reinterpret_cast<const float2*>(b)[lane];
    float2 o2;
    o2.x = (v.x - mu) * rinv * gg.x + bb.x;
    o2.y = (v.y - mu) * rinv * gg.y + bb.y;
    reinterpret_cast<float2*>(out + (size_t)wave * 128)[lane] = o2;
}

// residual LN: out = LN(xt + gat + gbias), in-place safe per row
__global__ __launch_bounds__(256) void ln_res_kernel(const float* __restrict__ xt,
                                                     const float* __restrict__ gat,
                                                     const float* __restrict__ gbias,
                                                     const float* __restrict__ g,
                                                     const float* __restrict__ b,
                                                     float* __restrict__ out, int n) {
    const int wave = (blockIdx.x * blockDim.x + threadIdx.x) >> 6;
    const int lane = threadIdx.x & 63;
    if (wave >= n) return;
    const float2 a = reinterpret_cast<const float2*>(xt + (size_t)wave * 128)[lane];
    const float2 c = reinterpret_cast<const float2*>(gat + (size_t)wave * 128)[lane];
    const float2 gb = reinterpret_cast<const float2*>(gbias)[lane];
    float2 v;
    v.x = a.x + c.x + gb.x;
    v.y = a.y + c.y + gb.y;
    float s = v.x + v.y;
    float sq = v.x * v.x + v.y * v.y;
#pragma unroll
    for (int o = 32; o; o >>= 1) { s += __shfl_xor(s, o); sq += __shfl_xor(sq, o); }
    const float mu = s * (1.f / 128.f);
    const float var = sq * (1.f / 128.f) - mu * mu;
    const float rinv = rsqrtf(var + LN_EPS);
    const float2 gg = reinterpret_cast<const float2*>(g)[lane];
    const float2 bb = reinterpret_cast<const float2*>(b)[lane];
    float2 o2;
    o2.x = (v.x - mu) * rinv * gg.x + bb.x;
    o2.y = (v.y - mu) * rinv * gg.y + bb.y;
    reinterpret_cast<float2*>(out + (size_t)wave * 128)[lane] = o2;
}

// ---------------- attention coefficients a_s, a_d per (node, head) ----------------
__global__ __launch_bounds__(256) void asad_kernel(const float* __restrict__ hW,
                                                   const float* __restrict__ att_s,
                                                   const float* __restrict__ att_d,
                                                   float* __restrict__ a_s,
                                                   float* __restrict__ a_d, int n) {
    const int idx = blockIdx.x * blockDim.x + threadIdx.x; // node*4 + h
    if (idx >= n * NHEAD) return;
    const int node = idx >> 2, h = idx & 3;
    const float4* hp = reinterpret_cast<const float4*>(hW + (size_t)node * 128 + h * 32);
    const float4* sp = reinterpret_cast<const float4*>(att_s + h * 32);
    const float4* dp = reinterpret_cast<const float4*>(att_d + h * 32);
    float ss = 0.f, dd = 0.f;
#pragma unroll
    for (int i = 0; i < 8; ++i) {
        const float4 hv = hp[i], sv = sp[i], dv = dp[i];
        ss += hv.x * sv.x + hv.y * sv.y + hv.z * sv.z + hv.w * sv.w;
        dd += hv.x * dv.x + hv.y * dv.y + hv.z * dv.z + hv.w * dv.w;
    }
    a_s[idx] = ss;
    a_d[idx] = dd;
}

// ---------------- init m=-inf, z=0, gat=0 ----------------
__global__ __launch_bounds__(256) void init_kernel(float* __restrict__ m,
                                                   float* __restrict__ z,
                                                   float* __restrict__ gat, int n) {
    const int i = blockIdx.x * blockDim.x + threadIdx.x;
    if (i < n * 128) gat[i] = 0.f;
    if (i < n * NHEAD) { m[i] = __int_as_float(0xFF800000); z[i] = 0.f; }
}

__device__ inline void atomicMaxFloat(float* addr, float val) {
    if (val >= 0.f) atomicMax(reinterpret_cast<int*>(addr), __float_as_int(val));
    else atomicMin(reinterpret_cast<unsigned int*>(addr), __float_as_uint(val));
}

// ---------------- edge pass 1: per-dst max ----------------
__global__ __launch_bounds__(256) void edge_max_kernel(const int* __restrict__ src,
                                                       const int* __restrict__ dst,
                                                       const float* __restrict__ a_s,
                                                       const float* __restrict__ a_d,
                                                       float* __restrict__ m,
                                                       int ne, int n) {
    const int e = blockIdx.x * blockDim.x + threadIdx.x;
    if (e >= ne + n) return;
    int s, d;
    if (e < ne) { s = src[e]; d = dst[e]; } else { s = d = e - ne; }
    const float4 as4 = *reinterpret_cast<const float4*>(a_s + (size_t)s * 4);
    const float4 ad4 = *reinterpret_cast<const float4*>(a_d + (size_t)d * 4);
    float ev[4] = {as4.x + ad4.x, as4.y + ad4.y, as4.z + ad4.z, as4.w + ad4.w};
#pragma unroll
    for (int h = 0; h < 4; ++h) {
        float x = ev[h];
        x = x > 0.f ? x : NEG_SLOPE * x;
        atomicMaxFloat(m + (size_t)d * 4 + h, x);
    }
}

// ---------------- edge pass 2: z = sum exp(e - m) ----------------
__global__ __launch_bounds__(256) void edge_sum_kernel(const int* __restrict__ src,
                                                       const int* __restrict__ dst,
                                                       const float* __restrict__ a_s,
                                                       const float* __restrict__ a_d,
                                                       const float* __restrict__ m,
                                                       float* __restrict__ z,
                                                       int ne, int n) {
    const int e = blockIdx.x * blockDim.x + threadIdx.x;
    if (e >= ne + n) return;
    int s, d;
    if (e < ne) { s = src[e]; d = dst[e]; } else { s = d = e - ne; }
    const float4 as4 = *reinterpret_cast<const float4*>(a_s + (size_t)s * 4);
    const float4 ad4 = *reinterpret_cast<const float4*>(a_d + (size_t)d * 4);
    const float4 m4 = *reinterpret_cast<const float4*>(m + (size_t)d * 4);
    float ev[4] = {as4.x + ad4.x, as4.y + ad4.y, as4.z + ad4.z, as4.w + ad4.w};
    const float mv[4] = {m4.x, m4.y, m4.z, m4.w};
#pragma unroll
    for (int h = 0; h < 4; ++h) {
        float x = ev[h];
        x = x > 0.f ? x : NEG_SLOPE * x;
        atomicAdd(z + (size_t)d * 4 + h, expf(x - mv[h]));
    }
}

// ---------------- edge pass 3: gat[d] += hW[s] * alpha (wave per edge) ----------------
__global__ __launch_bounds__(256) void edge_aggr_kernel(const int* __restrict__ src,
                                                        const int* __restrict__ dst,
                                                        const float* __restrict__ a_s,
                                                        const float* __restrict__ a_d,
                                                        const float* __restrict__ m,
                                                        const float* __restrict__ z,
                                                        const float* __restrict__ hW,
                                                        float* __restrict__ gat,
                                                        int ne, int n) {
    const int e = (blockIdx.x * blockDim.x + threadIdx.x) >> 6;
    const int lane = threadIdx.x & 63;
    if (e >= ne + n) return;
    int s, d;
    if (e < ne) { s = src[e]; d = dst[e]; } else { s = d = e - ne; }
    const int h = lane >> 4; // channels 2*lane, 2*lane+1 belong to head lane/16
    float x = a_s[(size_t)s * 4 + h] + a_d[(size_t)d * 4 + h];
    x = x > 0.f ? x : NEG_SLOPE * x;
    const float alpha = expf(x - m[(size_t)d * 4 + h]) / z[(size_t)d * 4 + h];
    const float2 hv = reinterpret_cast<const float2*>(hW + (size_t)s * 128)[lane];
    atomicAdd(gat + (size_t)d * 128 + 2 * lane, hv.x * alpha);
    atomicAdd(gat + (size_t)d * 128 + 2 * lane + 1, hv.y * alpha);
}

// ---------------- head: out[e] = relu(As[s]+Ad[d]) . W2 + b2 (wave per edge) --------
// (b1 is folded into As as the gemm bias)
__global__ __launch_bounds__(256) void head_kernel(const int* __restrict__ src,
                                                   const int* __restrict__ dst,
                                                   const float* __restrict__ As,
                                                   const float* __restrict__ Ad,
                                                   const float* __restrict__ W2,
                                                   const float* __restrict__ b2,
                                                   float* __restrict__ out, int ne) {
    const int e = (blockIdx.x * blockDim.x + threadIdx.x) >> 6;
    const int lane = threadIdx.x & 63;
    if (e >= ne) return;
    const int s = src[e], d = dst[e];
    const float2 a = reinterpret_cast<const float2*>(As + (size_t)s * 128)[lane];
    const float2 b = reinterpret_cast<const float2*>(Ad + (size_t)d * 128)[lane];
    const float2 w = reinterpret_cast<const float2*>(W2)[lane];
    float h0 = a.x + b.x; h0 = h0 > 0.f ? h0 : 0.f;
    float h1 = a.y + b.y; h1 = h1 > 0.f ? h1 : 0.f;
    float t = h0 * w.x + h1 * w.y;
#pragma unroll
    for (int o = 32; o; o >>= 1) t += __shfl_xor(t, o);
    if (lane == 0) out[e] = t + b2[0];
}

extern "C" void kernel_launch(void* const* d_in, const int* in_sizes, int n_in,
                              void* d_out, int out_size, void* d_ws, size_t ws_size,
                              hipStream_t stream) {
    const int N = NNODES, E = NEDGES;
    const float* x  = (const float*)d_in[0];
    const int* ei   = (const int*)d_in[1];
    const int* src  = ei;
    const int* dst  = ei + E;
    const float* Wp = (const float*)d_in[3];
    const float* bp = (const float*)d_in[4];
    const float* W1 = (const float*)d_in[5];
    const float* b1 = (const float*)d_in[6];
    const float* W2 = (const float*)d_in[7];
    const float* b2 = (const float*)d_in[8];

    float* ws = (float*)d_ws;
    float* h    = ws;                    // [N,128] : h / x_t (LN in place)
    float* bufB = h + (size_t)N * 128;   // [N,128] : hW / head As
    float* bufC = bufB + (size_t)N * 128;// [N,128] : gat accum / head Ad
    float* a_s  = bufC + (size_t)N * 128;// [N,4]
    float* a_d  = a_s + (size_t)N * 4;   // [N,4]
    float* mbuf = a_d + (size_t)N * 4;   // [N,4]
    float* zbuf = mbuf + (size_t)N * 4;  // [N,4]

    const int gemmGrid = N / 16;
    const int lnGrid = (N + 3) / 4;              // 4 waves (rows) per 256-thread block
    const int edgeTot = E + N;
    const int edgeGrid = (edgeTot + 255) / 256;
    const int aggrGrid = (edgeTot * 64 + 255) / 256;
    const int initGrid = (N * 128 + 255) / 256;
    const int asadGrid = (N * 4 + 255) / 256;

    // input projection: h = x @ Wp + bp
    gemm128<DIN, true><<<gemmGrid, 128, 0, stream>>>(x, Wp, bp, h);

    for (int L = 0; L < 2; ++L) {
        const int base = 9 + L * 8;
        const float* ln_a_g = (const float*)d_in[base + 0];
        const float* ln_a_b = (const float*)d_in[base + 1];
        const float* gW     = (const float*)d_in[base + 2];
        const float* gas    = (const float*)d_in[base + 3];
        const float* gad    = (const float*)d_in[base + 4];
        const float* gb     = (const float*)d_in[base + 5];
        const float* ln_b_g = (const float*)d_in[base + 6];
        const float* ln_b_b = (const float*)d_in[base + 7];

        ln_kernel<<<lnGrid, 256, 0, stream>>>(h, ln_a_g, ln_a_b, h, N);          // h := x_t
        gemm128<DH, false><<<gemmGrid, 128, 0, stream>>>(h, gW, nullptr, bufB);  // hW
        asad_kernel<<<asadGrid, 256, 0, stream>>>(bufB, gas, gad, a_s, a_d, N);
        init_kernel<<<initGrid, 256, 0, stream>>>(mbuf, zbuf, bufC, N);
        edge_max_kernel<<<edgeGrid, 256, 0, stream>>>(src, dst, a_s, a_d, mbuf, E, N);
        edge_sum_kernel<<<edgeGrid, 256, 0, stream>>>(src, dst, a_s, a_d, mbuf, zbuf, E, N);
        edge_aggr_kernel<<<aggrGrid, 256, 0, stream>>>(src, dst, a_s, a_d, mbuf, zbuf,
                                                       bufB, bufC, E, N);
        ln_res_kernel<<<lnGrid, 256, 0, stream>>>(h, bufC, gb, ln_b_g, ln_b_b, h, N);
    }

    // head: As = h@W1_top + b1 ; Ad = h@W1_bot ; out[e] = relu(As[s]+Ad[d]).W2 + b2
    gemm128<DH, true><<<gemmGrid, 128, 0, stream>>>(h, W1, b1, bufB);
    gemm128<DH, false><<<gemmGrid, 128, 0, stream>>>(h, W1 + 128 * 128, nullptr, bufC);
    head_kernel<<<(E * 64 + 255) / 256, 256, 0, stream>>>(src, dst, bufB, bufC, W2, b2,
                                                          (float*)d_out, E);
}

// Round 2
// 1881.158 us; speedup vs baseline: 1.3925x; 1.3925x over previous
//
#include <hip/hip_runtime.h>
#include <math.h>

#define NNODES 100000
#define NEDGES 500000
#define DIN 776
#define DH 128
#define NHEAD 4
#define NEG_SLOPE 0.2f
#define LN_EPS 1e-5f

typedef __attribute__((ext_vector_type(8))) short short8v;
typedef __attribute__((ext_vector_type(4))) float f32x4;

__device__ inline unsigned int f2bf_u(float f) {
    unsigned int u = __float_as_uint(f);
    return (u + 0x7fffu + ((u >> 16) & 1u)) >> 16;  // RNE, no NaN handling needed
}

// ---------- weight convert + transpose: W[K][128] f32 -> Bt[128][KP] bf16 (zero-pad K..KP)
__global__ __launch_bounds__(256) void conv_wt(const float* __restrict__ W,
                                               unsigned short* __restrict__ Bt,
                                               int K, int KP) {
    const int idx = blockIdx.x * 256 + threadIdx.x;
    if (idx >= 128 * KP) return;
    const int n = idx / KP, k = idx % KP;
    Bt[idx] = (k < K) ? (unsigned short)f2bf_u(W[(size_t)k * 128 + n]) : (unsigned short)0;
}

// ---------- MFMA GEMM: C[nrows,128] f32 = A[nrows,KA] @ B + bias
// A is fp32 (converted in staging) or bf16; B pre-converted transposed bf16 [128][KP].
// 256 threads, 128-row tile, 4 waves in 2x2, each wave 64x64 via 4x4 16x16x32 MFMAs.
template<int KP, bool ABF16, bool BIAS>
__global__ __launch_bounds__(256) void gemm_mfma(const void* __restrict__ Av,
                                                 const unsigned short* __restrict__ Bt,
                                                 const float* __restrict__ bias,
                                                 float* __restrict__ C,
                                                 int KA, int nrows) {
    constexpr int LS = 40;  // padded LDS row stride (bf16 elems): 80B -> ~2-way banks
    __shared__ unsigned short As[128 * LS];
    __shared__ unsigned short Bs[128 * LS];
    const int tid = threadIdx.x;
    const int row0 = blockIdx.x * 128;
    const int lane = tid & 63;
    const int wid = tid >> 6;
    const int wr = (wid >> 1) * 64, wc = (wid & 1) * 64;
    const int lrow = lane & 15, lk = (lane >> 4) * 8;
    const int srow = tid >> 1, sh = tid & 1;  // staging: thread -> (row, k-half)
    const bool rok = (row0 + srow) < nrows;

    f32x4 acc[4][4];
#pragma unroll
    for (int m = 0; m < 4; ++m)
#pragma unroll
        for (int n = 0; n < 4; ++n) acc[m][n] = (f32x4){0.f, 0.f, 0.f, 0.f};

    for (int k0 = 0; k0 < KP; k0 += 32) {
        const int kbase = k0 + sh * 16;
        // ---- stage A tile (128 x 32 bf16)
        if (ABF16) {
            const unsigned short* A = (const unsigned short*)Av;
            const unsigned short* ap = A + (size_t)(row0 + srow) * KA + kbase;
            uint4 q0 = {0u, 0u, 0u, 0u}, q1 = {0u, 0u, 0u, 0u};
            if (rok) {
                q0 = *(const uint4*)ap;
                q1 = *(const uint4*)(ap + 8);
            }
            *(uint4*)&As[srow * LS + sh * 16] = q0;
            *(uint4*)&As[srow * LS + sh * 16 + 8] = q1;
        } else {
            const float* A = (const float*)Av;
            const float* ap = A + (size_t)(row0 + srow) * KA + kbase;
            float4 f[4];
#pragma unroll
            for (int i = 0; i < 4; ++i) {
                const bool ok = rok && (kbase + i * 4 + 4 <= KA);
                f[i] = ok ? *(const float4*)(ap + i * 4) : make_float4(0.f, 0.f, 0.f, 0.f);
            }
            uint4 q0, q1;
            q0.x = f2bf_u(f[0].x) | (f2bf_u(f[0].y) << 16);
            q0.y = f2bf_u(f[0].z) | (f2bf_u(f[0].w) << 16);
            q0.z = f2bf_u(f[1].x) | (f2bf_u(f[1].y) << 16);
            q0.w = f2bf_u(f[1].z) | (f2bf_u(f[1].w) << 16);
            q1.x = f2bf_u(f[2].x) | (f2bf_u(f[2].y) << 16);
            q1.y = f2bf_u(f[2].z) | (f2bf_u(f[2].w) << 16);
            q1.z = f2bf_u(f[3].x) | (f2bf_u(f[3].y) << 16);
            q1.w = f2bf_u(f[3].z) | (f2bf_u(f[3].w) << 16);
            *(uint4*)&As[srow * LS + sh * 16] = q0;
            *(uint4*)&As[srow * LS + sh * 16 + 8] = q1;
        }
        // ---- stage B tile (128 cols x 32 k, from transposed bf16 weights)
        {
            const unsigned short* bp = Bt + (size_t)srow * KP + kbase;
            *(uint4*)&Bs[srow * LS + sh * 16] = *(const uint4*)bp;
            *(uint4*)&Bs[srow * LS + sh * 16 + 8] = *(const uint4*)(bp + 8);
        }
        __syncthreads();
        short8v a[4], b[4];
#pragma unroll
        for (int m = 0; m < 4; ++m)
            a[m] = *(const short8v*)&As[(wr + m * 16 + lrow) * LS + lk];
#pragma unroll
        for (int n = 0; n < 4; ++n)
            b[n] = *(const short8v*)&Bs[(wc + n * 16 + lrow) * LS + lk];
#pragma unroll
        for (int m = 0; m < 4; ++m)
#pragma unroll
            for (int n = 0; n < 4; ++n)
                acc[m][n] = __builtin_amdgcn_mfma_f32_16x16x32_bf16(a[m], b[n], acc[m][n], 0, 0, 0);
        __syncthreads();
    }

    float bv[4];
#pragma unroll
    for (int n = 0; n < 4; ++n) bv[n] = BIAS ? bias[wc + n * 16 + lrow] : 0.f;
#pragma unroll
    for (int m = 0; m < 4; ++m) {
        const int rbase = row0 + wr + m * 16 + (lane >> 4) * 4;
#pragma unroll
        for (int j = 0; j < 4; ++j) {
            const int r = rbase + j;
            if (r < nrows) {
#pragma unroll
                for (int n = 0; n < 4; ++n)
                    C[(size_t)r * 128 + wc + n * 16 + lrow] = acc[m][n][j] + bv[n];
            }
        }
    }
}

// ---------------- LayerNorm (wave per row); writes f32 + bf16 copies ----------------
__global__ __launch_bounds__(256) void ln_kernel(const float* __restrict__ in,
                                                 const float* __restrict__ g,
                                                 const float* __restrict__ b,
                                                 float* __restrict__ out,
                                                 unsigned short* __restrict__ outb, int n) {
    const int wave = (blockIdx.x * blockDim.x + threadIdx.x) >> 6;
    const int lane = threadIdx.x & 63;
    if (wave >= n) return;
    const float2 v = reinterpret_cast<const float2*>(in + (size_t)wave * 128)[lane];
    float s = v.x + v.y;
    float sq = v.x * v.x + v.y * v.y;
#pragma unroll
    for (int o = 32; o; o >>= 1) { s += __shfl_xor(s, o); sq += __shfl_xor(sq, o); }
    const float mu = s * (1.f / 128.f);
    const float var = sq * (1.f / 128.f) - mu * mu;
    const float rinv = rsqrtf(var + LN_EPS);
    const float2 gg = reinterpret_cast<const float2*>(g)[lane];
    const float2 bb = reinterpret_cast<const float2*>(b)[lane];
    float2 o2;
    o2.x = (v.x - mu) * rinv * gg.x + bb.x;
    o2.y = (v.y - mu) * rinv * gg.y + bb.y;
    reinterpret_cast<float2*>(out + (size_t)wave * 128)[lane] = o2;
    reinterpret_cast<unsigned int*>(outb + (size_t)wave * 128)[lane] =
        f2bf_u(o2.x) | (f2bf_u(o2.y) << 16);
}

// residual LN: out = LN(xt + gat + gbias); writes f32 + bf16
__global__ __launch_bounds__(256) void ln_res_kernel(const float* __restrict__ xt,
                                                     const float* __restrict__ gat,
                                                     const float* __restrict__ gbias,
                                                     const float* __restrict__ g,
                                                     const float* __restrict__ b,
                                                     float* __restrict__ out,
                                                     unsigned short* __restrict__ outb, int n) {
    const int wave = (blockIdx.x * blockDim.x + threadIdx.x) >> 6;
    const int lane = threadIdx.x & 63;
    if (wave >= n) return;
    const float2 a = reinterpret_cast<const float2*>(xt + (size_t)wave * 128)[lane];
    const float2 c = reinterpret_cast<const float2*>(gat + (size_t)wave * 128)[lane];
    const float2 gb = reinterpret_cast<const float2*>(gbias)[lane];
    float2 v;
    v.x = a.x + c.x + gb.x;
    v.y = a.y + c.y + gb.y;
    float s = v.x + v.y;
    float sq = v.x * v.x + v.y * v.y;
#pragma unroll
    for (int o = 32; o; o >>= 1) { s += __shfl_xor(s, o); sq += __shfl_xor(sq, o); }
    const float mu = s * (1.f / 128.f);
    const float var = sq * (1.f / 128.f) - mu * mu;
    const float rinv = rsqrtf(var + LN_EPS);
    const float2 gg = reinterpret_cast<const float2*>(g)[lane];
    const float2 bb = reinterpret_cast<const float2*>(b)[lane];
    float2 o2;
    o2.x = (v.x - mu) * rinv * gg.x + bb.x;
    o2.y = (v.y - mu) * rinv * gg.y + bb.y;
    reinterpret_cast<float2*>(out + (size_t)wave * 128)[lane] = o2;
    reinterpret_cast<unsigned int*>(outb + (size_t)wave * 128)[lane] =
        f2bf_u(o2.x) | (f2bf_u(o2.y) << 16);
}

// ---------------- attention coefficients a_s, a_d per (node, head) ----------------
__global__ __launch_bounds__(256) void asad_kernel(const float* __restrict__ hW,
                                                   const float* __restrict__ att_s,
                                                   const float* __restrict__ att_d,
                                                   float* __restrict__ a_s,
                                                   float* __restrict__ a_d, int n) {
    const int idx = blockIdx.x * blockDim.x + threadIdx.x; // node*4 + h
    if (idx >= n * NHEAD) return;
    const int node = idx >> 2, h = idx & 3;
    const float4* hp = reinterpret_cast<const float4*>(hW + (size_t)node * 128 + h * 32);
    const float4* sp = reinterpret_cast<const float4*>(att_s + h * 32);
    const float4* dp = reinterpret_cast<const float4*>(att_d + h * 32);
    float ss = 0.f, dd = 0.f;
#pragma unroll
    for (int i = 0; i < 8; ++i) {
        const float4 hv = hp[i], sv = sp[i], dv = dp[i];
        ss += hv.x * sv.x + hv.y * sv.y + hv.z * sv.z + hv.w * sv.w;
        dd += hv.x * dv.x + hv.y * dv.y + hv.z * dv.z + hv.w * dv.w;
    }
    a_s[idx] = ss;
    a_d[idx] = dd;
}

// ---------------- init m=-inf, z=0, gat=0 ----------------
__global__ __launch_bounds__(256) void init_kernel(float* __restrict__ m,
                                                   float* __restrict__ z,
                                                   float* __restrict__ gat, int n) {
    const int i = blockIdx.x * blockDim.x + threadIdx.x;
    if (i < n * 128) gat[i] = 0.f;
    if (i < n * NHEAD) { m[i] = __int_as_float(0xFF800000); z[i] = 0.f; }
}

__device__ inline void atomicMaxFloat(float* addr, float val) {
    if (val >= 0.f) atomicMax(reinterpret_cast<int*>(addr), __float_as_int(val));
    else atomicMin(reinterpret_cast<unsigned int*>(addr), __float_as_uint(val));
}

// ---------------- edge pass 1: per-dst max ----------------
__global__ __launch_bounds__(256) void edge_max_kernel(const int* __restrict__ src,
                                                       const int* __restrict__ dst,
                                                       const float* __restrict__ a_s,
                                                       const float* __restrict__ a_d,
                                                       float* __restrict__ m,
                                                       int ne, int n) {
    const int e = blockIdx.x * blockDim.x + threadIdx.x;
    if (e >= ne + n) return;
    int s, d;
    if (e < ne) { s = src[e]; d = dst[e]; } else { s = d = e - ne; }
    const float4 as4 = *reinterpret_cast<const float4*>(a_s + (size_t)s * 4);
    const float4 ad4 = *reinterpret_cast<const float4*>(a_d + (size_t)d * 4);
    float ev[4] = {as4.x + ad4.x, as4.y + ad4.y, as4.z + ad4.z, as4.w + ad4.w};
#pragma unroll
    for (int h = 0; h < 4; ++h) {
        float x = ev[h];
        x = x > 0.f ? x : NEG_SLOPE * x;
        atomicMaxFloat(m + (size_t)d * 4 + h, x);
    }
}

// ---------------- edge pass 2: z = sum exp(e - m) ----------------
__global__ __launch_bounds__(256) void edge_sum_kernel(const int* __restrict__ src,
                                                       const int* __restrict__ dst,
                                                       const float* __restrict__ a_s,
                                                       const float* __restrict__ a_d,
                                                       const float* __restrict__ m,
                                                       float* __restrict__ z,
                                                       int ne, int n) {
    const int e = blockIdx.x * blockDim.x + threadIdx.x;
    if (e >= ne + n) return;
    int s, d;
    if (e < ne) { s = src[e]; d = dst[e]; } else { s = d = e - ne; }
    const float4 as4 = *reinterpret_cast<const float4*>(a_s + (size_t)s * 4);
    const float4 ad4 = *reinterpret_cast<const float4*>(a_d + (size_t)d * 4);
    const float4 m4 = *reinterpret_cast<const float4*>(m + (size_t)d * 4);
    float ev[4] = {as4.x + ad4.x, as4.y + ad4.y, as4.z + ad4.z, as4.w + ad4.w};
    const float mv[4] = {m4.x, m4.y, m4.z, m4.w};
#pragma unroll
    for (int h = 0; h < 4; ++h) {
        float x = ev[h];
        x = x > 0.f ? x : NEG_SLOPE * x;
        atomicAdd(z + (size_t)d * 4 + h, expf(x - mv[h]));
    }
}

// ---------------- edge pass 3: gat[d] += hW[s] * alpha (wave per edge) ----------------
__global__ __launch_bounds__(256) void edge_aggr_kernel(const int* __restrict__ src,
                                                        const int* __restrict__ dst,
                                                        const float* __restrict__ a_s,
                                                        const float* __restrict__ a_d,
                                                        const float* __restrict__ m,
                                                        const float* __restrict__ z,
                                                        const float* __restrict__ hW,
                                                        float* __restrict__ gat,
                                                        int ne, int n) {
    const int e = (blockIdx.x * blockDim.x + threadIdx.x) >> 6;
    const int lane = threadIdx.x & 63;
    if (e >= ne + n) return;
    int s, d;
    if (e < ne) { s = src[e]; d = dst[e]; } else { s = d = e - ne; }
    const int h = lane >> 4;
    float x = a_s[(size_t)s * 4 + h] + a_d[(size_t)d * 4 + h];
    x = x > 0.f ? x : NEG_SLOPE * x;
    const float alpha = expf(x - m[(size_t)d * 4 + h]) / z[(size_t)d * 4 + h];
    const float2 hv = reinterpret_cast<const float2*>(hW + (size_t)s * 128)[lane];
    atomicAdd(gat + (size_t)d * 128 + 2 * lane, hv.x * alpha);
    atomicAdd(gat + (size_t)d * 128 + 2 * lane + 1, hv.y * alpha);
}

// ---------------- head: out[e] = relu(As[s]+Ad[d]) . W2 + b2 (wave per edge) --------
__global__ __launch_bounds__(256) void head_kernel(const int* __restrict__ src,
                                                   const int* __restrict__ dst,
                                                   const float* __restrict__ As,
                                                   const float* __restrict__ Ad,
                                                   const float* __restrict__ W2,
                                                   const float* __restrict__ b2,
                                                   float* __restrict__ out, int ne) {
    const int e = (blockIdx.x * blockDim.x + threadIdx.x) >> 6;
    const int lane = threadIdx.x & 63;
    if (e >= ne) return;
    const int s = src[e], d = dst[e];
    const float2 a = reinterpret_cast<const float2*>(As + (size_t)s * 128)[lane];
    const float2 b = reinterpret_cast<const float2*>(Ad + (size_t)d * 128)[lane];
    const float2 w = reinterpret_cast<const float2*>(W2)[lane];
    float h0 = a.x + b.x; h0 = h0 > 0.f ? h0 : 0.f;
    float h1 = a.y + b.y; h1 = h1 > 0.f ? h1 : 0.f;
    float t = h0 * w.x + h1 * w.y;
#pragma unroll
    for (int o = 32; o; o >>= 1) t += __shfl_xor(t, o);
    if (lane == 0) out[e] = t + b2[0];
}

extern "C" void kernel_launch(void* const* d_in, const int* in_sizes, int n_in,
                              void* d_out, int out_size, void* d_ws, size_t ws_size,
                              hipStream_t stream) {
    const int N = NNODES, E = NEDGES;
    const float* x  = (const float*)d_in[0];
    const int* ei   = (const int*)d_in[1];
    const int* src  = ei;
    const int* dst  = ei + E;
    const float* Wp = (const float*)d_in[3];
    const float* bp = (const float*)d_in[4];
    const float* W1 = (const float*)d_in[5];
    const float* b1 = (const float*)d_in[6];
    const float* W2 = (const float*)d_in[7];
    const float* b2 = (const float*)d_in[8];

    float* ws = (float*)d_ws;
    float* h    = ws;                     // [N,128]
    float* bufB = h + (size_t)N * 128;    // [N,128] : hW / head As
    float* bufC = bufB + (size_t)N * 128; // [N,128] : gat accum / head Ad
    float* a_s  = bufC + (size_t)N * 128; // [N,4]
    float* a_d  = a_s + (size_t)N * 4;
    float* mbuf = a_d + (size_t)N * 4;
    float* zbuf = mbuf + (size_t)N * 4;
    unsigned short* actb = (unsigned short*)(zbuf + (size_t)N * 4); // [N,128] bf16
    unsigned short* BtP  = actb + (size_t)N * 128;  // [128][800] bf16
    unsigned short* BtG  = BtP + 128 * 800;         // [128][128]
    unsigned short* Bt1a = BtG + 128 * 128;
    unsigned short* Bt1b = Bt1a + 128 * 128;

    const int gemmGrid = (N + 127) / 128;  // 782
    const int lnGrid = (N + 3) / 4;
    const int edgeTot = E + N;
    const int edgeGrid = (edgeTot + 255) / 256;
    const int aggrGrid = (edgeTot * 64 + 255) / 256;
    const int initGrid = (N * 128 + 255) / 256;
    const int asadGrid = (N * 4 + 255) / 256;

    // input projection: h = x @ Wp + bp  (bf16 MFMA, K padded 776->800)
    conv_wt<<<(128 * 800 + 255) / 256, 256, 0, stream>>>(Wp, BtP, DIN, 800);
    gemm_mfma<800, false, true><<<gemmGrid, 256, 0, stream>>>(x, BtP, bp, h, DIN, N);

    for (int L = 0; L < 2; ++L) {
        const int base = 9 + L * 8;
        const float* ln_a_g = (const float*)d_in[base + 0];
        const float* ln_a_b = (const float*)d_in[base + 1];
        const float* gW     = (const float*)d_in[base + 2];
        const float* gas    = (const float*)d_in[base + 3];
        const float* gad    = (const float*)d_in[base + 4];
        const float* gb     = (const float*)d_in[base + 5];
        const float* ln_b_g = (const float*)d_in[base + 6];
        const float* ln_b_b = (const float*)d_in[base + 7];

        conv_wt<<<(128 * 128 + 255) / 256, 256, 0, stream>>>(gW, BtG, DH, DH);
        ln_kernel<<<lnGrid, 256, 0, stream>>>(h, ln_a_g, ln_a_b, h, actb, N);
        gemm_mfma<128, true, false><<<gemmGrid, 256, 0, stream>>>(actb, BtG, nullptr, bufB, DH, N);
        asad_kernel<<<asadGrid, 256, 0, stream>>>(bufB, gas, gad, a_s, a_d, N);
        init_kernel<<<initGrid, 256, 0, stream>>>(mbuf, zbuf, bufC, N);
        edge_max_kernel<<<edgeGrid, 256, 0, stream>>>(src, dst, a_s, a_d, mbuf, E, N);
        edge_sum_kernel<<<edgeGrid, 256, 0, stream>>>(src, dst, a_s, a_d, mbuf, zbuf, E, N);
        edge_aggr_kernel<<<aggrGrid, 256, 0, stream>>>(src, dst, a_s, a_d, mbuf, zbuf,
                                                       bufB, bufC, E, N);
        ln_res_kernel<<<lnGrid, 256, 0, stream>>>(h, bufC, gb, ln_b_g, ln_b_b, h, actb, N);
    }

    // head: As = h@W1_top + b1 ; Ad = h@W1_bot ; out[e] = relu(As[s]+Ad[d]).W2 + b2
    conv_wt<<<(128 * 128 + 255) / 256, 256, 0, stream>>>(W1, Bt1a, DH, DH);
    conv_wt<<<(128 * 128 + 255) / 256, 256, 0, stream>>>(W1 + 128 * 128, Bt1b, DH, DH);
    gemm_mfma<128, true, true><<<gemmGrid, 256, 0, stream>>>(actb, Bt1a, b1, bufB, DH, N);
    gemm_mfma<128, true, false><<<gemmGrid, 256, 0, stream>>>(actb, Bt1b, nullptr, bufC, DH, N);
    head_kernel<<<(E * 64 + 255) / 256, 256, 0, stream>>>(src, dst, bufB, bufC, W2, b2,
                                                          (float*)d_out, E);
}

// Round 3
// 756.315 us; speedup vs baseline: 3.4634x; 2.4873x over previous
//
#include <hip/hip_runtime.h>
#include <math.h>

#define NNODES 100000
#define NEDGES 500000
#define DIN 776
#define DH 128
#define NHEAD 4
#define NEG_SLOPE 0.2f
#define LN_EPS 1e-5f

typedef __attribute__((ext_vector_type(8))) short short8v;
typedef __attribute__((ext_vector_type(4))) float f32x4;

__device__ inline unsigned int f2bf_u(float f) {
    unsigned int u = __float_as_uint(f);
    return (u + 0x7fffu + ((u >> 16) & 1u)) >> 16;  // RNE
}

// ---------- weight convert + transpose: W[K][128] f32 -> Bt[128][KP] bf16 (zero-pad)
__global__ __launch_bounds__(256) void conv_wt(const float* __restrict__ W,
                                               unsigned short* __restrict__ Bt,
                                               int K, int KP) {
    const int idx = blockIdx.x * 256 + threadIdx.x;
    if (idx >= 128 * KP) return;
    const int n = idx / KP, k = idx % KP;
    Bt[idx] = (k < K) ? (unsigned short)f2bf_u(W[(size_t)k * 128 + n]) : (unsigned short)0;
}

// ---------- MFMA GEMM: C[nrows,128] f32 = A[nrows,KA] @ B + bias ----------
template<int KP, bool ABF16, bool BIAS>
__global__ __launch_bounds__(256) void gemm_mfma(const void* __restrict__ Av,
                                                 const unsigned short* __restrict__ Bt,
                                                 const float* __restrict__ bias,
                                                 float* __restrict__ C,
                                                 int KA, int nrows) {
    constexpr int LS = 40;
    __shared__ unsigned short As[128 * LS];
    __shared__ unsigned short Bs[128 * LS];
    const int tid = threadIdx.x;
    const int row0 = blockIdx.x * 128;
    const int lane = tid & 63;
    const int wid = tid >> 6;
    const int wr = (wid >> 1) * 64, wc = (wid & 1) * 64;
    const int lrow = lane & 15, lk = (lane >> 4) * 8;
    const int srow = tid >> 1, sh = tid & 1;
    const bool rok = (row0 + srow) < nrows;

    f32x4 acc[4][4];
#pragma unroll
    for (int m = 0; m < 4; ++m)
#pragma unroll
        for (int n = 0; n < 4; ++n) acc[m][n] = (f32x4){0.f, 0.f, 0.f, 0.f};

    for (int k0 = 0; k0 < KP; k0 += 32) {
        const int kbase = k0 + sh * 16;
        if (ABF16) {
            const unsigned short* A = (const unsigned short*)Av;
            const unsigned short* ap = A + (size_t)(row0 + srow) * KA + kbase;
            uint4 q0 = {0u, 0u, 0u, 0u}, q1 = {0u, 0u, 0u, 0u};
            if (rok) {
                q0 = *(const uint4*)ap;
                q1 = *(const uint4*)(ap + 8);
            }
            *(uint4*)&As[srow * LS + sh * 16] = q0;
            *(uint4*)&As[srow * LS + sh * 16 + 8] = q1;
        } else {
            const float* A = (const float*)Av;
            const float* ap = A + (size_t)(row0 + srow) * KA + kbase;
            float4 f[4];
#pragma unroll
            for (int i = 0; i < 4; ++i) {
                const bool ok = rok && (kbase + i * 4 + 4 <= KA);
                f[i] = ok ? *(const float4*)(ap + i * 4) : make_float4(0.f, 0.f, 0.f, 0.f);
            }
            uint4 q0, q1;
            q0.x = f2bf_u(f[0].x) | (f2bf_u(f[0].y) << 16);
            q0.y = f2bf_u(f[0].z) | (f2bf_u(f[0].w) << 16);
            q0.z = f2bf_u(f[1].x) | (f2bf_u(f[1].y) << 16);
            q0.w = f2bf_u(f[1].z) | (f2bf_u(f[1].w) << 16);
            q1.x = f2bf_u(f[2].x) | (f2bf_u(f[2].y) << 16);
            q1.y = f2bf_u(f[2].z) | (f2bf_u(f[2].w) << 16);
            q1.z = f2bf_u(f[3].x) | (f2bf_u(f[3].y) << 16);
            q1.w = f2bf_u(f[3].z) | (f2bf_u(f[3].w) << 16);
            *(uint4*)&As[srow * LS + sh * 16] = q0;
            *(uint4*)&As[srow * LS + sh * 16 + 8] = q1;
        }
        {
            const unsigned short* bp = Bt + (size_t)srow * KP + kbase;
            *(uint4*)&Bs[srow * LS + sh * 16] = *(const uint4*)bp;
            *(uint4*)&Bs[srow * LS + sh * 16 + 8] = *(const uint4*)(bp + 8);
        }
        __syncthreads();
        short8v a[4], b[4];
#pragma unroll
        for (int m = 0; m < 4; ++m)
            a[m] = *(const short8v*)&As[(wr + m * 16 + lrow) * LS + lk];
#pragma unroll
        for (int n = 0; n < 4; ++n)
            b[n] = *(const short8v*)&Bs[(wc + n * 16 + lrow) * LS + lk];
#pragma unroll
        for (int m = 0; m < 4; ++m)
#pragma unroll
            for (int n = 0; n < 4; ++n)
                acc[m][n] = __builtin_amdgcn_mfma_f32_16x16x32_bf16(a[m], b[n], acc[m][n], 0, 0, 0);
        __syncthreads();
    }

    float bv[4];
#pragma unroll
    for (int n = 0; n < 4; ++n) bv[n] = BIAS ? bias[wc + n * 16 + lrow] : 0.f;
#pragma unroll
    for (int m = 0; m < 4; ++m) {
        const int rbase = row0 + wr + m * 16 + (lane >> 4) * 4;
#pragma unroll
        for (int j = 0; j < 4; ++j) {
            const int r = rbase + j;
            if (r < nrows) {
#pragma unroll
                for (int n = 0; n < 4; ++n)
                    C[(size_t)r * 128 + wc + n * 16 + lrow] = acc[m][n][j] + bv[n];
            }
        }
    }
}

// ---------------- LayerNorm (wave per row); writes f32 + bf16 ----------------
__global__ __launch_bounds__(256) void ln_kernel(const float* __restrict__ in,
                                                 const float* __restrict__ g,
                                                 const float* __restrict__ b,
                                                 float* __restrict__ out,
                                                 unsigned short* __restrict__ outb, int n) {
    const int wave = (blockIdx.x * blockDim.x + threadIdx.x) >> 6;
    const int lane = threadIdx.x & 63;
    if (wave >= n) return;
    const float2 v = reinterpret_cast<const float2*>(in + (size_t)wave * 128)[lane];
    float s = v.x + v.y;
    float sq = v.x * v.x + v.y * v.y;
#pragma unroll
    for (int o = 32; o; o >>= 1) { s += __shfl_xor(s, o); sq += __shfl_xor(sq, o); }
    const float mu = s * (1.f / 128.f);
    const float var = sq * (1.f / 128.f) - mu * mu;
    const float rinv = rsqrtf(var + LN_EPS);
    const float2 gg = reinterpret_cast<const float2*>(g)[lane];
    const float2 bb = reinterpret_cast<const float2*>(b)[lane];
    float2 o2;
    o2.x = (v.x - mu) * rinv * gg.x + bb.x;
    o2.y = (v.y - mu) * rinv * gg.y + bb.y;
    reinterpret_cast<float2*>(out + (size_t)wave * 128)[lane] = o2;
    reinterpret_cast<unsigned int*>(outb + (size_t)wave * 128)[lane] =
        f2bf_u(o2.x) | (f2bf_u(o2.y) << 16);
}

__global__ __launch_bounds__(256) void ln_res_kernel(const float* __restrict__ xt,
                                                     const float* __restrict__ gat,
                                                     const float* __restrict__ gbias,
                                                     const float* __restrict__ g,
                                                     const float* __restrict__ b,
                                                     float* __restrict__ out,
                                                     unsigned short* __restrict__ outb, int n) {
    const int wave = (blockIdx.x * blockDim.x + threadIdx.x) >> 6;
    const int lane = threadIdx.x & 63;
    if (wave >= n) return;
    const float2 a = reinterpret_cast<const float2*>(xt + (size_t)wave * 128)[lane];
    const float2 c = reinterpret_cast<const float2*>(gat + (size_t)wave * 128)[lane];
    const float2 gb = reinterpret_cast<const float2*>(gbias)[lane];
    float2 v;
    v.x = a.x + c.x + gb.x;
    v.y = a.y + c.y + gb.y;
    float s = v.x + v.y;
    float sq = v.x * v.x + v.y * v.y;
#pragma unroll
    for (int o = 32; o; o >>= 1) { s += __shfl_xor(s, o); sq += __shfl_xor(sq, o); }
    const float mu = s * (1.f / 128.f);
    const float var = sq * (1.f / 128.f) - mu * mu;
    const float rinv = rsqrtf(var + LN_EPS);
    const float2 gg = reinterpret_cast<const float2*>(g)[lane];
    const float2 bb = reinterpret_cast<const float2*>(b)[lane];
    float2 o2;
    o2.x = (v.x - mu) * rinv * gg.x + bb.x;
    o2.y = (v.y - mu) * rinv * gg.y + bb.y;
    reinterpret_cast<float2*>(out + (size_t)wave * 128)[lane] = o2;
    reinterpret_cast<unsigned int*>(outb + (size_t)wave * 128)[lane] =
        f2bf_u(o2.x) | (f2bf_u(o2.y) << 16);
}

// ---------------- a_s, a_d per (node, head) ----------------
__global__ __launch_bounds__(256) void asad_kernel(const float* __restrict__ hW,
                                                   const float* __restrict__ att_s,
                                                   const float* __restrict__ att_d,
                                                   float* __restrict__ a_s,
                                                   float* __restrict__ a_d, int n) {
    const int idx = blockIdx.x * blockDim.x + threadIdx.x;
    if (idx >= n * NHEAD) return;
    const int node = idx >> 2, h = idx & 3;
    const float4* hp = reinterpret_cast<const float4*>(hW + (size_t)node * 128 + h * 32);
    const float4* sp = reinterpret_cast<const float4*>(att_s + h * 32);
    const float4* dp = reinterpret_cast<const float4*>(att_d + h * 32);
    float ss = 0.f, dd = 0.f;
#pragma unroll
    for (int i = 0; i < 8; ++i) {
        const float4 hv = hp[i], sv = sp[i], dv = dp[i];
        ss += hv.x * sv.x + hv.y * sv.y + hv.z * sv.z + hv.w * sv.w;
        dd += hv.x * dv.x + hv.y * dv.y + hv.z * dv.z + hv.w * dv.w;
    }
    a_s[idx] = ss;
    a_d[idx] = dd;
}

// ================= CSR build (once per launch, shared by both layers) =================
__global__ __launch_bounds__(256) void csr_zero(int* __restrict__ cnt, int n) {
    const int i = blockIdx.x * 256 + threadIdx.x;
    if (i < n) cnt[i] = 0;
}

__global__ __launch_bounds__(256) void csr_hist(const int* __restrict__ dst,
                                                int* __restrict__ cnt, int ne, int n) {
    const int e = blockIdx.x * 256 + threadIdx.x;
    if (e >= ne + n) return;
    const int d = (e < ne) ? dst[e] : (e - ne);
    atomicAdd(&cnt[d], 1);
}

// block-level exclusive scan; writes per-block sums
__global__ __launch_bounds__(256) void csr_scan1(const int* __restrict__ cnt,
                                                 int* __restrict__ offs,
                                                 int* __restrict__ bsum, int n) {
    __shared__ int lds[256];
    const int i = blockIdx.x * 256 + threadIdx.x;
    int v = (i < n) ? cnt[i] : 0;
    lds[threadIdx.x] = v;
    __syncthreads();
    int acc = v;
#pragma unroll
    for (int o = 1; o < 256; o <<= 1) {
        int t = (threadIdx.x >= o) ? lds[threadIdx.x - o] : 0;
        __syncthreads();
        acc += t;
        lds[threadIdx.x] = acc;
        __syncthreads();
    }
    if (i < n) offs[i] = acc - v;  // exclusive within block
    if (threadIdx.x == 255) bsum[blockIdx.x] = acc;
}

// single-block scan of block sums (nb <= 512)
__global__ __launch_bounds__(512) void csr_scan2(int* __restrict__ bsum, int nb) {
    __shared__ int lds[512];
    const int t = threadIdx.x;
    int v = (t < nb) ? bsum[t] : 0;
    lds[t] = v;
    __syncthreads();
    int acc = v;
#pragma unroll
    for (int o = 1; o < 512; o <<= 1) {
        int x = (t >= o) ? lds[t - o] : 0;
        __syncthreads();
        acc += x;
        lds[t] = acc;
        __syncthreads();
    }
    if (t < nb) bsum[t] = acc - v;  // exclusive
}

__global__ __launch_bounds__(256) void csr_scan3(int* __restrict__ offs,
                                                 const int* __restrict__ bsum,
                                                 int* __restrict__ cur, int n, int total) {
    const int i = blockIdx.x * 256 + threadIdx.x;
    if (i < n) {
        const int o = offs[i] + bsum[blockIdx.x];
        offs[i] = o;
        cur[i] = o;
    }
    if (i == 0) offs[n] = total;
}

__global__ __launch_bounds__(256) void csr_scatter(const int* __restrict__ src,
                                                   const int* __restrict__ dst,
                                                   int* __restrict__ cur,
                                                   int* __restrict__ csr, int ne, int n) {
    const int e = blockIdx.x * 256 + threadIdx.x;
    if (e >= ne + n) return;
    int s, d;
    if (e < ne) { s = src[e]; d = dst[e]; } else { s = d = e - ne; }
    const int slot = atomicAdd(&cur[d], 1);
    csr[slot] = s;
}

// ========== CSR aggregation: wave per dst, softmax + weighted sum, no atomics ==========
__global__ __launch_bounds__(256) void aggr_csr_kernel(const int* __restrict__ csr,
                                                       const int* __restrict__ offs,
                                                       const float* __restrict__ a_s,
                                                       const float* __restrict__ a_d,
                                                       const float* __restrict__ hW,
                                                       float* __restrict__ gat, int n) {
    const int d = (blockIdx.x * blockDim.x + threadIdx.x) >> 6;
    const int lane = threadIdx.x & 63;
    if (d >= n) return;
    const int h = lane >> 4;
    const int beg = offs[d], end = offs[d + 1];
    const float ad = a_d[(size_t)d * 4 + h];

    float m = -1e30f;
    for (int j = beg; j < end; ++j) {
        const int s = csr[j];
        float x = a_s[(size_t)s * 4 + h] + ad;
        x = x > 0.f ? x : NEG_SLOPE * x;
        m = fmaxf(m, x);
    }
    float z = 0.f;
    float accx = 0.f, accy = 0.f;
    for (int j = beg; j < end; ++j) {
        const int s = csr[j];
        float x = a_s[(size_t)s * 4 + h] + ad;
        x = x > 0.f ? x : NEG_SLOPE * x;
        const float p = expf(x - m);
        z += p;
        const float2 hv = reinterpret_cast<const float2*>(hW + (size_t)s * 128)[lane];
        accx += p * hv.x;
        accy += p * hv.y;
    }
    const float rz = 1.f / z;
    float2 o2;
    o2.x = accx * rz;
    o2.y = accy * rz;
    reinterpret_cast<float2*>(gat + (size_t)d * 128)[lane] = o2;
}

// ---------------- head: out[e] = relu(As[s]+Ad[d]) . W2 + b2 (wave per edge) ----------
__global__ __launch_bounds__(256) void head_kernel(const int* __restrict__ src,
                                                   const int* __restrict__ dst,
                                                   const float* __restrict__ As,
                                                   const float* __restrict__ Ad,
                                                   const float* __restrict__ W2,
                                                   const float* __restrict__ b2,
                                                   float* __restrict__ out, int ne) {
    const int e = (blockIdx.x * blockDim.x + threadIdx.x) >> 6;
    const int lane = threadIdx.x & 63;
    if (e >= ne) return;
    const int s = src[e], d = dst[e];
    const float2 a = reinterpret_cast<const float2*>(As + (size_t)s * 128)[lane];
    const float2 b = reinterpret_cast<const float2*>(Ad + (size_t)d * 128)[lane];
    const float2 w = reinterpret_cast<const float2*>(W2)[lane];
    float h0 = a.x + b.x; h0 = h0 > 0.f ? h0 : 0.f;
    float h1 = a.y + b.y; h1 = h1 > 0.f ? h1 : 0.f;
    float t = h0 * w.x + h1 * w.y;
#pragma unroll
    for (int o = 32; o; o >>= 1) t += __shfl_xor(t, o);
    if (lane == 0) out[e] = t + b2[0];
}

extern "C" void kernel_launch(void* const* d_in, const int* in_sizes, int n_in,
                              void* d_out, int out_size, void* d_ws, size_t ws_size,
                              hipStream_t stream) {
    const int N = NNODES, E = NEDGES;
    const float* x  = (const float*)d_in[0];
    const int* ei   = (const int*)d_in[1];
    const int* src  = ei;
    const int* dst  = ei + E;
    const float* Wp = (const float*)d_in[3];
    const float* bp = (const float*)d_in[4];
    const float* W1 = (const float*)d_in[5];
    const float* b1 = (const float*)d_in[6];
    const float* W2 = (const float*)d_in[7];
    const float* b2 = (const float*)d_in[8];

    float* ws = (float*)d_ws;
    float* h    = ws;                     // [N,128]
    float* bufB = h + (size_t)N * 128;    // [N,128] : hW / head As
    float* bufC = bufB + (size_t)N * 128; // [N,128] : gat / head Ad
    float* a_s  = bufC + (size_t)N * 128; // [N,4]
    float* a_d  = a_s + (size_t)N * 4;
    unsigned short* actb = (unsigned short*)(a_d + (size_t)N * 4); // [N,128] bf16
    unsigned short* BtP  = actb + (size_t)N * 128;  // [128][800]
    unsigned short* BtG  = BtP + 128 * 800;
    unsigned short* Bt1a = BtG + 128 * 128;
    unsigned short* Bt1b = Bt1a + 128 * 128;
    int* cnt  = (int*)(Bt1b + 128 * 128); // [N] histogram / scatter cursor
    int* offs = cnt + N;                  // [N+1]
    int* bsum = offs + N + 1;             // [512]
    int* csr  = bsum + 512;               // [E+N]

    const int gemmGrid = (N + 127) / 128;
    const int lnGrid = (N + 3) / 4;
    const int edgeTot = E + N;
    const int edgeGrid = (edgeTot + 255) / 256;
    const int nodeGrid = (N + 255) / 256;
    const int scanBlocks = (N + 255) / 256;  // 391
    const int aggrGrid = (N * 64 + 255) / 256;
    const int asadGrid = (N * 4 + 255) / 256;

    // ---- CSR build (once; reused by both layers)
    csr_zero<<<nodeGrid, 256, 0, stream>>>(cnt, N);
    csr_hist<<<edgeGrid, 256, 0, stream>>>(dst, cnt, E, N);
    csr_scan1<<<scanBlocks, 256, 0, stream>>>(cnt, offs, bsum, N);
    csr_scan2<<<1, 512, 0, stream>>>(bsum, scanBlocks);
    csr_scan3<<<scanBlocks, 256, 0, stream>>>(offs, bsum, cnt, N, edgeTot);
    csr_scatter<<<edgeGrid, 256, 0, stream>>>(src, dst, cnt, csr, E, N);

    // ---- input projection
    conv_wt<<<(128 * 800 + 255) / 256, 256, 0, stream>>>(Wp, BtP, DIN, 800);
    gemm_mfma<800, false, true><<<gemmGrid, 256, 0, stream>>>(x, BtP, bp, h, DIN, N);

    for (int L = 0; L < 2; ++L) {
        const int base = 9 + L * 8;
        const float* ln_a_g = (const float*)d_in[base + 0];
        const float* ln_a_b = (const float*)d_in[base + 1];
        const float* gW     = (const float*)d_in[base + 2];
        const float* gas    = (const float*)d_in[base + 3];
        const float* gad    = (const float*)d_in[base + 4];
        const float* gb     = (const float*)d_in[base + 5];
        const float* ln_b_g = (const float*)d_in[base + 6];
        const float* ln_b_b = (const float*)d_in[base + 7];

        conv_wt<<<(128 * 128 + 255) / 256, 256, 0, stream>>>(gW, BtG, DH, DH);
        ln_kernel<<<lnGrid, 256, 0, stream>>>(h, ln_a_g, ln_a_b, h, actb, N);
        gemm_mfma<128, true, false><<<gemmGrid, 256, 0, stream>>>(actb, BtG, nullptr, bufB, DH, N);
        asad_kernel<<<asadGrid, 256, 0, stream>>>(bufB, gas, gad, a_s, a_d, N);
        aggr_csr_kernel<<<aggrGrid, 256, 0, stream>>>(csr, offs, a_s, a_d, bufB, bufC, N);
        ln_res_kernel<<<lnGrid, 256, 0, stream>>>(h, bufC, gb, ln_b_g, ln_b_b, h, actb, N);
    }

    // ---- head
    conv_wt<<<(128 * 128 + 255) / 256, 256, 0, stream>>>(W1, Bt1a, DH, DH);
    conv_wt<<<(128 * 128 + 255) / 256, 256, 0, stream>>>(W1 + 128 * 128, Bt1b, DH, DH);
    gemm_mfma<128, true, true><<<gemmGrid, 256, 0, stream>>>(actb, Bt1a, b1, bufB, DH, N);
    gemm_mfma<128, true, false><<<gemmGrid, 256, 0, stream>>>(actb, Bt1b, nullptr, bufC, DH, N);
    head_kernel<<<(E * 64 + 255) / 256, 256, 0, stream>>>(src, dst, bufB, bufC, W2, b2,
                                                          (float*)d_out, E);
}